// Round 10
// baseline (74.668 us; speedup 1.0000x reference)
//
#include <hip/hip_runtime.h>

// QLinear: y[n,o] = round((sum_k (x[n,k]-xz)*(w[o,k]-wz) + bias[o]) * M + yz)
// N=65536, K=512, OUT=512.
// Exact i8 path: (x-128),(w-128) in [-128,127]; |dot+bias| < 2^24; f32 epilogue exact.
// R10: tile 64 x 512 (FULL output width) -> x f32 read exactly once, W from L2.
//      Per K-step 36KB staged/block (A 16KB reg->i8, B 32KB global_load_lds).
//      8 waves (2x4), wave-tile 32x128. Fragment-major LDS. Plain __syncthreads.

#define K_DIM 512
#define OUTF  512
#define NT    8                  // K_DIM / 64
#define B_OFF 4096               // A: 4 frags x 1KB; B: 32 frags x 1KB
#define BUF_B (4096 + 32768)     // 36864 per buffer

typedef __attribute__((ext_vector_type(4))) int   i32x4;
typedef __attribute__((ext_vector_type(4))) float f32x4;
typedef __attribute__((ext_vector_type(2))) unsigned int u32x2;

__device__ __forceinline__ void gload16(const void* g, void* l) {
    __builtin_amdgcn_global_load_lds(
        (const __attribute__((address_space(1))) void*)g,
        (__attribute__((address_space(3))) void*)l, 16, 0, 0);
}

// ---------- prepass: weight int32 -> i8 (w - wz), row-major [o][k] ----------
__global__ void wprep(const int* __restrict__ W, unsigned int* __restrict__ Wb,
                      const float* __restrict__ wzp) {
    const int wz = __float2int_rn(wzp[0]);
    int idx = (blockIdx.x * blockDim.x + threadIdx.x) * 4;
    i32x4 w = *reinterpret_cast<const i32x4*>(W + idx);
    unsigned int p = ((unsigned int)(w[0] - wz) & 0xffu)
                   | (((unsigned int)(w[1] - wz) & 0xffu) << 8)
                   | (((unsigned int)(w[2] - wz) & 0xffu) << 16)
                   | (((unsigned int)(w[3] - wz) & 0xffu) << 24);
    Wb[idx >> 2] = p;
}

__global__ __launch_bounds__(512, 4)
void qgemm(const float* __restrict__ X,
           const unsigned char* __restrict__ Wb,
           const int* __restrict__ bias,
           const float* __restrict__ Mp,
           const float* __restrict__ xzp,
           const float* __restrict__ yzp,
           float* __restrict__ Y) {
    __shared__ unsigned char lds[2][BUF_B];   // 73728 B total

    const int tid  = threadIdx.x;
    const int lane = tid & 63;
    const int wid  = tid >> 6;                 // 0..7
    const int wr   = wid >> 2;                 // row-group (0..1): rows wr*32
    const int wc   = wid & 3;                  // col-group (0..3): cols wc*128
    const int fr   = lane & 15;
    const int fq   = lane >> 4;

    const int row0 = blockIdx.x * 64;          // full-width tile: no col redundancy

    const float xzf = xzp[0];

    // ---- A staging map: thread -> row (tid>>3), 8 f32 at k-bytes (tid&7)*8 ----
    const int arow  = tid >> 3;                // 0..63
    const int kslot = tid & 7;                 // 8B granules
    const float* xbase = X + (size_t)(row0 + arow) * K_DIM + kslot * 8;
    // fragment-major dest: frag arow>>4, lane (arow&15)+(kslot>>1)*16, half kslot&1
    const int dA = (arow >> 4) * 1024 + (((arow & 15) + ((kslot >> 1) << 4)) << 4)
                 + ((kslot & 1) << 3);

    // ---- B staging: wave wid stages frags 4*wid..4*wid+3 via global_load_lds ----
    // frag f = W rows (cols of y) f*16..+15; lane l -> row f*16+(l&15), k-bytes (l>>4)*16.
    const unsigned char* wbase = Wb + (size_t)(wid * 64 + fr) * K_DIM + fq * 16;
    const int ldsB = B_OFF + wid * 4096;

    f32x4 ra[2][2];                            // dist-2 staging sets (8 f32 each)

    auto stageA = [&](int t) {
        const int s = t & 1;
        const float* p = xbase + t * 64;
        ra[s][0] = *reinterpret_cast<const f32x4*>(p);
        ra[s][1] = *reinterpret_cast<const f32x4*>(p + 4);
    };
    auto gloadB = [&](int t, int buf) {
        const unsigned char* g = wbase + t * 64;
        #pragma unroll
        for (int f = 0; f < 4; ++f)
            gload16(g + (size_t)f * 16 * K_DIM, &lds[buf][ldsB + f * 1024]);
    };
    auto convwriteA = [&](int t) {
        const int s = t & 1;
        u32x2 v;
        #pragma unroll
        for (int h = 0; h < 2; ++h) {
            unsigned int u0 = (unsigned int)((int)(ra[s][h][0] - xzf)) & 0xffu;
            unsigned int u1 = (unsigned int)((int)(ra[s][h][1] - xzf)) & 0xffu;
            unsigned int u2 = (unsigned int)((int)(ra[s][h][2] - xzf)) & 0xffu;
            unsigned int u3 = (unsigned int)((int)(ra[s][h][3] - xzf)) & 0xffu;
            v[h] = u0 | (u1 << 8) | (u2 << 16) | (u3 << 24);
        }
        *reinterpret_cast<u32x2*>(&lds[s][dA]) = v;
    };

    // bias folded into accumulator init; wave-tile 32x128: acc[m][n], m=0..1, n=0..7
    const int c0 = wc * 128;
    i32x4 acc[2][8];
    #pragma unroll
    for (int n = 0; n < 8; ++n) {
        const int bv = bias[c0 + n * 16 + fr];
        acc[0][n] = i32x4{bv, bv, bv, bv};
        acc[1][n] = i32x4{bv, bv, bv, bv};
    }

    const int aBase = (wr * 2) * 1024 + lane * 16;           // A frags 2wr, 2wr+1
    const int bBase = B_OFF + (wc * 8) * 1024 + lane * 16;   // B frags 8wc..8wc+7

    auto compute = [&](int t) {
        const int s = t & 1;
        i32x4 af0 = *reinterpret_cast<const i32x4*>(&lds[s][aBase]);
        i32x4 af1 = *reinterpret_cast<const i32x4*>(&lds[s][aBase + 1024]);
        #pragma unroll
        for (int n = 0; n < 8; ++n) {
            i32x4 bf = *reinterpret_cast<const i32x4*>(&lds[s][bBase + n * 1024]);
            acc[0][n] = __builtin_amdgcn_mfma_i32_16x16x64_i8(af0, bf, acc[0][n], 0, 0, 0);
            acc[1][n] = __builtin_amdgcn_mfma_i32_16x16x64_i8(af1, bf, acc[1][n], 0, 0, 0);
        }
    };

    // prologue: A t=0,1 in flight; B t=0 in flight; write A t=0; drain
    stageA(0);
    stageA(1);
    gloadB(0, 0);
    convwriteA(0);
    __syncthreads();

    #pragma unroll
    for (int t = 0; t < NT; ++t) {
        if (t + 2 < NT) stageA(t + 2);              // far-ahead A issue first
        if (t + 1 < NT) gloadB(t + 1, (t + 1) & 1); // next-tile B into other buffer
        compute(t);
        if (t + 1 < NT) convwriteA(t + 1);          // consume 1-iter-old A loads
        __syncthreads();
    }

    // epilogue: y = rintf(acc * M + yz)   (bias pre-folded)
    const float Mv = Mp[0], yz = yzp[0];
    #pragma unroll
    for (int m = 0; m < 2; ++m) {
        const int row = row0 + wr * 32 + m * 16 + fq * 4;
        #pragma unroll
        for (int n = 0; n < 8; ++n) {
            float* yp = Y + (size_t)row * OUTF + c0 + n * 16 + fr;
            #pragma unroll
            for (int j = 0; j < 4; ++j)
                yp[(size_t)j * OUTF] = rintf((float)acc[m][n][j] * Mv + yz);
        }
    }
}

extern "C" void kernel_launch(void* const* d_in, const int* in_sizes, int n_in,
                              void* d_out, int out_size, void* d_ws, size_t ws_size,
                              hipStream_t stream) {
    const float* x    = (const float*)d_in[0];
    const int*   w    = (const int*)d_in[1];
    const int*   bias = (const int*)d_in[2];
    const float* M    = (const float*)d_in[3];
    const float* xz   = (const float*)d_in[4];
    const float* wz   = (const float*)d_in[5];
    const float* yz   = (const float*)d_in[6];
    float* y = (float*)d_out;

    unsigned int* Wb = (unsigned int*)d_ws;     // 512*512 i8 = 256 KB

    wprep<<<256, 256, 0, stream>>>(w, Wb, wz);
    qgemm<<<1024, 512, 0, stream>>>(x, (const unsigned char*)Wb, bias, M, xz, yz, y);
}